// Round 1
// 17397.697 us; speedup vs baseline: 1.3620x; 1.3620x over previous
//
#include <hip/hip_runtime.h>

#define T_STEPS 70
#define BATCH   64
#define NTOKEN  33278
#define NINP    400
#define NHID    1150
#define MROWS   (T_STEPS * BATCH)   // 4480

typedef unsigned short u16;
typedef __attribute__((ext_vector_type(8))) short bf16x8;
typedef __attribute__((ext_vector_type(4))) float f32x4;

// ---------------- embedding gather: A[m][i] = emb_w[tok[m]][i] ----------------
__global__ __launch_bounds__(256) void embed_kernel(const int* __restrict__ tok,
                                                    const float* __restrict__ emb_w,
                                                    float* __restrict__ A) {
    int idx = blockIdx.x * 256 + threadIdx.x;           // m*NINP + i
    if (idx >= MROWS * NINP) return;
    int m = idx / NINP, i = idx - m * NINP;
    int t = tok[m];
    A[idx] = emb_w[(size_t)t * NINP + i];
}

// ---------------- fp32 copy ----------------
__global__ __launch_bounds__(256) void copy_kernel(const float* __restrict__ src,
                                                   float* __restrict__ dst, int n) {
    int idx = blockIdx.x * 256 + threadIdx.x;
    if (idx < n) dst[idx] = src[idx];
}

// ---------------- fp32 -> bf16 hi/lo split with K padding ----------------
__device__ __forceinline__ u16 f2bf_rn(float x) {
    union { float f; unsigned u; } v; v.f = x;
    unsigned u = v.u;
    unsigned r = u + 0x7fffu + ((u >> 16) & 1u);   // RNE
    return (u16)(r >> 16);
}
__device__ __forceinline__ float bf2f(u16 h) {
    union { float f; unsigned u; } v; v.u = ((unsigned)h) << 16;
    return v.f;
}
__global__ __launch_bounds__(256) void split_kernel(const float* __restrict__ src,
                                                    u16* __restrict__ hi,
                                                    u16* __restrict__ lo,
                                                    int R, int K, int Kp) {
    int idx = blockIdx.x * 256 + threadIdx.x;
    if (idx >= R * Kp) return;
    int r = idx / Kp, k = idx - r * Kp;
    float a = (k < K) ? src[(size_t)r * K + k] : 0.f;
    u16 h = f2bf_rn(a);
    float rem = a - bf2f(h);
    hi[idx] = h;
    lo[idx] = f2bf_rn(rem);
}

// ---------------- split-bf16 MFMA GEMM: C[m][n] = A[m][:] . W[n][:] + bias[n] ----------------
// A,W given as bf16 hi/lo pairs, row-major M x Kp / N x Kp, Kp % 32 == 0.
// acc = Ah*Wh + Ah*Wl + Al*Wh  (drops Al*Wl, ~2^-18 relative -> fp32-grade)
// 128x128 tile, BK=32, 256 threads = 4 waves (2x2), each wave 64x64 = 4x4 frags of 16x16x32.
#define GLL16(g, l) __builtin_amdgcn_global_load_lds(                                   \
    (const __attribute__((address_space(1))) unsigned int*)(g),                         \
    (__attribute__((address_space(3))) unsigned int*)(l), 16, 0, 0)

__global__ __launch_bounds__(256) void gemm_mfma(const u16* __restrict__ Ah,
                                                 const u16* __restrict__ Al,
                                                 const u16* __restrict__ Wh,
                                                 const u16* __restrict__ Wl,
                                                 const float* __restrict__ bias,
                                                 float* __restrict__ C,
                                                 int M, int N, int Kp) {
    __shared__ u16 sAh[128 * 32];
    __shared__ u16 sAl[128 * 32];
    __shared__ u16 sWh[128 * 32];
    __shared__ u16 sWl[128 * 32];

    int tid  = threadIdx.x;
    int lane = tid & 63;
    int w    = tid >> 6;
    int wrow = (w >> 1) * 64;
    int wcol = (w & 1) * 64;
    int row0 = blockIdx.x * 128;
    int col0 = blockIdx.y * 128;

    // staging geometry: 512 chunks of 16B per 8KB tile; 2 chunks/thread/tile.
    // chunk c -> LDS u16 index c*8 == [row=c/4][k=(c&3)*8] of a [128][32] tile.
    int c0 = tid, c1 = tid + 256;
    int r0 = c0 >> 2, kb0 = (c0 & 3) * 8;
    int r1 = c1 >> 2, kb1 = (c1 & 3) * 8;
    int ar0 = row0 + r0; if (ar0 >= M) ar0 = M - 1;
    int ar1 = row0 + r1; if (ar1 >= M) ar1 = M - 1;
    int nr0 = col0 + r0; if (nr0 >= N) nr0 = N - 1;
    int nr1 = col0 + r1; if (nr1 >= N) nr1 = N - 1;

    const u16* pAh0 = Ah + (size_t)ar0 * Kp + kb0;
    const u16* pAh1 = Ah + (size_t)ar1 * Kp + kb1;
    const u16* pAl0 = Al + (size_t)ar0 * Kp + kb0;
    const u16* pAl1 = Al + (size_t)ar1 * Kp + kb1;
    const u16* pWh0 = Wh + (size_t)nr0 * Kp + kb0;
    const u16* pWh1 = Wh + (size_t)nr1 * Kp + kb1;
    const u16* pWl0 = Wl + (size_t)nr0 * Kp + kb0;
    const u16* pWl1 = Wl + (size_t)nr1 * Kp + kb1;

    int fr = lane & 15;            // fragment row (M or N within 16)
    int fk = (lane >> 4) * 8;      // fragment k offset

    f32x4 acc[4][4] = {};

    for (int k0 = 0; k0 < Kp; k0 += 32) {
        GLL16(pAh0 + k0, &sAh[c0 * 8]);
        GLL16(pAh1 + k0, &sAh[c1 * 8]);
        GLL16(pAl0 + k0, &sAl[c0 * 8]);
        GLL16(pAl1 + k0, &sAl[c1 * 8]);
        GLL16(pWh0 + k0, &sWh[c0 * 8]);
        GLL16(pWh1 + k0, &sWh[c1 * 8]);
        GLL16(pWl0 + k0, &sWl[c0 * 8]);
        GLL16(pWl1 + k0, &sWl[c1 * 8]);
        __syncthreads();   // compiler drains vmcnt before s_barrier

        bf16x8 ah[4], al[4], wh[4], wl[4];
#pragma unroll
        for (int i = 0; i < 4; ++i) {
            ah[i] = *(const bf16x8*)&sAh[(wrow + i * 16 + fr) * 32 + fk];
            al[i] = *(const bf16x8*)&sAl[(wrow + i * 16 + fr) * 32 + fk];
            wh[i] = *(const bf16x8*)&sWh[(wcol + i * 16 + fr) * 32 + fk];
            wl[i] = *(const bf16x8*)&sWl[(wcol + i * 16 + fr) * 32 + fk];
        }
#pragma unroll
        for (int mi = 0; mi < 4; ++mi) {
#pragma unroll
            for (int ni = 0; ni < 4; ++ni) {
                acc[mi][ni] = __builtin_amdgcn_mfma_f32_16x16x32_bf16(ah[mi], wh[ni], acc[mi][ni], 0, 0, 0);
                acc[mi][ni] = __builtin_amdgcn_mfma_f32_16x16x32_bf16(ah[mi], wl[ni], acc[mi][ni], 0, 0, 0);
                acc[mi][ni] = __builtin_amdgcn_mfma_f32_16x16x32_bf16(al[mi], wh[ni], acc[mi][ni], 0, 0, 0);
            }
        }
        __syncthreads();
    }

    // C/D layout (m89-verified): col = lane&15, row = (lane>>4)*4 + reg
    int crow = row0 + wrow + (lane >> 4) * 4;
    int ccol = col0 + wcol + (lane & 15);
#pragma unroll
    for (int ni = 0; ni < 4; ++ni) {
        int col = ccol + ni * 16;
        if (col >= N) continue;
        float bv = bias[col];
#pragma unroll
        for (int mi = 0; mi < 4; ++mi) {
#pragma unroll
            for (int j = 0; j < 4; ++j) {
                int row = crow + mi * 16 + j;
                if (row < M) C[(size_t)row * N + col] = acc[mi][ni][j] + bv;
            }
        }
    }
}

// ---------------- one LSTM timestep, fused: pre = xpre + h@wh^T + bh; gates; c,h ----------------
__global__ __launch_bounds__(256) void lstm_step(const float* __restrict__ xpre,  // B x 4n
                                                 const float* __restrict__ hprev, // B x n
                                                 float* __restrict__ c,           // B x n (in place)
                                                 const float* __restrict__ wh,    // 4n x n
                                                 const float* __restrict__ bh,    // 4n
                                                 float* __restrict__ hout,        // B x n
                                                 int n) {
    __shared__ float Hs[64][33];
    __shared__ float Ws[16][33];
    int tid = threadIdx.x;
    int b = tid & 63, jj = tid >> 6;
    int j = blockIdx.x * 4 + jj;
    float accf = 0.f, acci = 0.f, acco = 0.f, accg = 0.f;
    for (int k0 = 0; k0 < n; k0 += 32) {
        for (int r = 0; r < 8; ++r) {
            int idx = tid + r * 256;
            int hb = idx >> 5, kk = idx & 31;
            int k = k0 + kk;
            Hs[hb][kk] = (k < n) ? hprev[hb * n + k] : 0.f;
        }
        for (int r = 0; r < 2; ++r) {
            int idx = tid + r * 256;
            int wr = idx >> 5, kk = idx & 31;
            int gi = wr >> 2, jr = wr & 3;
            int jb = blockIdx.x * 4 + jr;
            int k = k0 + kk;
            Ws[wr][kk] = (jb < n && k < n) ? wh[(size_t)(gi * n + jb) * n + k] : 0.f;
        }
        __syncthreads();
#pragma unroll
        for (int kk = 0; kk < 32; ++kk) {
            float hv = Hs[b][kk];
            accf += hv * Ws[jj][kk];
            acci += hv * Ws[4 + jj][kk];
            acco += hv * Ws[8 + jj][kk];
            accg += hv * Ws[12 + jj][kk];
        }
        __syncthreads();
    }
    if (j < n) {
        int g4 = 4 * n;
        float pf = accf + xpre[b * g4 + j]         + bh[j];
        float pi = acci + xpre[b * g4 + n + j]     + bh[n + j];
        float po = acco + xpre[b * g4 + 2 * n + j] + bh[2 * n + j];
        float pg = accg + xpre[b * g4 + 3 * n + j] + bh[3 * n + j];
        float f = 1.f / (1.f + expf(-pf));
        float i = 1.f / (1.f + expf(-pi));
        float o = 1.f / (1.f + expf(-po));
        float g = tanhf(pg);
        float cn = f * c[b * n + j] + i * g;
        c[b * n + j] = cn;
        hout[b * n + j] = o * tanhf(cn);
    }
}

extern "C" void kernel_launch(void* const* d_in, const int* in_sizes, int n_in,
                              void* d_out, int out_size, void* d_ws, size_t ws_size,
                              hipStream_t stream) {
    const int*   tok   = (const int*)d_in[0];
    const float* h0    = (const float*)d_in[1];
    const float* c0    = (const float*)d_in[2];
    const float* h1    = (const float*)d_in[3];
    const float* c1    = (const float*)d_in[4];
    const float* h2    = (const float*)d_in[5];
    const float* c2    = (const float*)d_in[6];
    const float* emb_w = (const float*)d_in[7];
    const float* wi[3] = {(const float*)d_in[8],  (const float*)d_in[12], (const float*)d_in[16]};
    const float* bi[3] = {(const float*)d_in[9],  (const float*)d_in[13], (const float*)d_in[17]};
    const float* wh[3] = {(const float*)d_in[10], (const float*)d_in[14], (const float*)d_in[18]};
    const float* bh[3] = {(const float*)d_in[11], (const float*)d_in[15], (const float*)d_in[19]};
    const float* dec_b = (const float*)d_in[20];
    const float* hinit[3] = {h0, h1, h2};
    const float* cinit[3] = {c0, c2 == c2 ? c1 : c1, c2};   // keep order explicit below
    const int din[3]  = {NINP, NHID, NHID};
    const int dout[3] = {NHID, NHID, NINP};
    const float* cinits[3] = {c0, c1, c2};

    // ---- workspace layout (bytes) ----
    // bufA   [0,           20,608,000)   activations ping   (4480*1150 f32)
    // bufB   [20,608,000,  41,216,000)   activations pong
    // P      [41,216,000, 123,648,000)   x_pre (4480*4600 f32); decoder W-split reuses this
    // cb     [123,648,000, 123,942,400)  c-state f32
    // A2h    [123,942,400, 134,264,320)  act split hi  (4480*1152 bf16)
    // A2l    [134,264,320, 144,586,240)  act split lo
    // W2h    [144,586,240, 155,184,640)  wi split hi   (4600*1152 bf16)
    // W2l    [155,184,640, 165,783,040)  wi split lo
    char* base = (char*)d_ws;
    float* bufA = (float*)(base);
    float* bufB = (float*)(base + 20608000);
    float* P    = (float*)(base + 41216000);
    float* cb   = (float*)(base + 123648000);
    u16* A2h = (u16*)(base + 123942400);
    u16* A2l = (u16*)(base + 134264320);
    u16* W2h = (u16*)(base + 144586240);
    u16* W2l = (u16*)(base + 155184640);
    u16* DWh = (u16*)(base + 41216000);                 // 33278*416*2 = 27,687,296 B
    u16* DWl = (u16*)(base + 41216000 + 27687296);      // both inside P region

    // 1) embedding -> bufA
    embed_kernel<<<(MROWS * NINP + 255) / 256, 256, 0, stream>>>(tok, emb_w, bufA);

    float* xs = bufA;   // current layer input (M x din)
    float* hs = bufB;   // current layer output (M x dout)
    for (int l = 0; l < 3; ++l) {
        int G  = 4 * dout[l];
        int K  = din[l];
        int Kp = (K + 31) & ~31;
        // 2) split weights + activations to bf16 hi/lo (zero-padded K)
        split_kernel<<<((size_t)G * Kp + 255) / 256, 256, 0, stream>>>(wi[l], W2h, W2l, G, K, Kp);
        split_kernel<<<((size_t)MROWS * Kp + 255) / 256, 256, 0, stream>>>(xs, A2h, A2l, MROWS, K, Kp);
        // 3) x_pre = xs @ wi^T + bi   (M x G) via MFMA
        dim3 g1(MROWS / 128, (G + 127) / 128);
        gemm_mfma<<<g1, 256, 0, stream>>>(A2h, A2l, W2h, W2l, bi[l], P, MROWS, G, Kp);
        // 4) init c state
        int bn = BATCH * dout[l];
        copy_kernel<<<(bn + 255) / 256, 256, 0, stream>>>(cinits[l], cb, bn);
        // 5) scan
        for (int t = 0; t < T_STEPS; ++t) {
            const float* hp = (t == 0) ? hinit[l] : hs + (size_t)(t - 1) * BATCH * dout[l];
            lstm_step<<<(dout[l] + 3) / 4, 256, 0, stream>>>(
                P + (size_t)t * BATCH * G, hp, cb, wh[l], bh[l],
                hs + (size_t)t * BATCH * dout[l], dout[l]);
        }
        float* tmp = xs; xs = hs; hs = tmp;
    }

    // 6) decoder: out = xs @ emb_w^T + dec_b  (4480 x 33278) via MFMA
    {
        int K = NINP, Kp = 416;
        split_kernel<<<((size_t)NTOKEN * Kp + 255) / 256, 256, 0, stream>>>(emb_w, DWh, DWl, NTOKEN, K, Kp);
        split_kernel<<<((size_t)MROWS * Kp + 255) / 256, 256, 0, stream>>>(xs, A2h, A2l, MROWS, K, Kp);
        dim3 g2(MROWS / 128, (NTOKEN + 127) / 128);
        gemm_mfma<<<g2, 256, 0, stream>>>(A2h, A2l, DWh, DWl, dec_b, (float*)d_out, MROWS, NTOKEN, Kp);
    }
}

// Round 2
// 7707.770 us; speedup vs baseline: 3.0744x; 2.2572x over previous
//
#include <hip/hip_runtime.h>

#define T_STEPS 70
#define BATCH   64
#define NTOKEN  33278
#define NINP    400
#define NHID    1150
#define MROWS   (T_STEPS * BATCH)   // 4480

typedef unsigned short u16;
typedef __attribute__((ext_vector_type(8))) short bf16x8;
typedef __attribute__((ext_vector_type(4))) float f32x4;

// ---------------- fp32 -> bf16 hi/lo split helpers ----------------
__device__ __forceinline__ u16 f2bf_rn(float x) {
    union { float f; unsigned u; } v; v.f = x;
    unsigned u = v.u;
    unsigned r = u + 0x7fffu + ((u >> 16) & 1u);   // RNE
    return (u16)(r >> 16);
}
__device__ __forceinline__ float bf2f(u16 h) {
    union { float f; unsigned u; } v; v.u = ((unsigned)h) << 16;
    return v.f;
}

// ---------------- fused embedding gather + split (layer-0 A operand) ----------------
__global__ __launch_bounds__(256) void embed_split(const int* __restrict__ tok,
                                                   const float* __restrict__ emb_w,
                                                   u16* __restrict__ hi,
                                                   u16* __restrict__ lo) {
    int idx = blockIdx.x * 256 + threadIdx.x;     // m*416 + k
    if (idx >= MROWS * 416) return;
    int m = idx / 416, k = idx - m * 416;
    float v = 0.f;
    if (k < NINP) v = emb_w[(size_t)tok[m] * NINP + k];
    u16 h = f2bf_rn(v);
    hi[idx] = h;
    lo[idx] = f2bf_rn(v - bf2f(h));
}

// ---------------- fp32 copy ----------------
__global__ __launch_bounds__(256) void copy_kernel(const float* __restrict__ src,
                                                   float* __restrict__ dst, int n) {
    int idx = blockIdx.x * 256 + threadIdx.x;
    if (idx < n) dst[idx] = src[idx];
}

// ---------------- generic fp32 -> bf16 hi/lo split with K padding ----------------
__global__ __launch_bounds__(256) void split_kernel(const float* __restrict__ src,
                                                    u16* __restrict__ hi,
                                                    u16* __restrict__ lo,
                                                    int R, int K, int Kp) {
    int idx = blockIdx.x * 256 + threadIdx.x;
    if (idx >= R * Kp) return;
    int r = idx / Kp, k = idx - r * Kp;
    float a = (k < K) ? src[(size_t)r * K + k] : 0.f;
    u16 h = f2bf_rn(a);
    float rem = a - bf2f(h);
    hi[idx] = h;
    lo[idx] = f2bf_rn(rem);
}

// ---------------- wh (4n x n) -> split hi/lo, shape 4 x np x Kp (row/K zero-padded) ----------------
__global__ __launch_bounds__(256) void split_wh_kernel(const float* __restrict__ wh,
                                                       u16* __restrict__ hi,
                                                       u16* __restrict__ lo,
                                                       int n, int np, int Kp) {
    int idx = blockIdx.x * 256 + threadIdx.x;
    int total = 4 * np * Kp;
    if (idx >= total) return;
    int g  = idx / (np * Kp);
    int r  = idx - g * np * Kp;
    int jj = r / Kp, k = r - jj * Kp;
    float v = (jj < n && k < n) ? wh[(size_t)(g * n + jj) * n + k] : 0.f;
    u16 h = f2bf_rn(v);
    hi[idx] = h;
    lo[idx] = f2bf_rn(v - bf2f(h));
}

// ---------------- split-bf16 MFMA GEMM (unchanged from R1) ----------------
#define GLL16(g, l) __builtin_amdgcn_global_load_lds(                                   \
    (const __attribute__((address_space(1))) unsigned int*)(g),                         \
    (__attribute__((address_space(3))) unsigned int*)(l), 16, 0, 0)

__global__ __launch_bounds__(256) void gemm_mfma(const u16* __restrict__ Ah,
                                                 const u16* __restrict__ Al,
                                                 const u16* __restrict__ Wh,
                                                 const u16* __restrict__ Wl,
                                                 const float* __restrict__ bias,
                                                 float* __restrict__ C,
                                                 int M, int N, int Kp) {
    __shared__ u16 sAh[128 * 32];
    __shared__ u16 sAl[128 * 32];
    __shared__ u16 sWh[128 * 32];
    __shared__ u16 sWl[128 * 32];

    int tid  = threadIdx.x;
    int lane = tid & 63;
    int w    = tid >> 6;
    int wrow = (w >> 1) * 64;
    int wcol = (w & 1) * 64;
    int row0 = blockIdx.x * 128;
    int col0 = blockIdx.y * 128;

    int c0 = tid, c1 = tid + 256;
    int r0 = c0 >> 2, kb0 = (c0 & 3) * 8;
    int r1 = c1 >> 2, kb1 = (c1 & 3) * 8;
    int ar0 = row0 + r0; if (ar0 >= M) ar0 = M - 1;
    int ar1 = row0 + r1; if (ar1 >= M) ar1 = M - 1;
    int nr0 = col0 + r0; if (nr0 >= N) nr0 = N - 1;
    int nr1 = col0 + r1; if (nr1 >= N) nr1 = N - 1;

    const u16* pAh0 = Ah + (size_t)ar0 * Kp + kb0;
    const u16* pAh1 = Ah + (size_t)ar1 * Kp + kb1;
    const u16* pAl0 = Al + (size_t)ar0 * Kp + kb0;
    const u16* pAl1 = Al + (size_t)ar1 * Kp + kb1;
    const u16* pWh0 = Wh + (size_t)nr0 * Kp + kb0;
    const u16* pWh1 = Wh + (size_t)nr1 * Kp + kb1;
    const u16* pWl0 = Wl + (size_t)nr0 * Kp + kb0;
    const u16* pWl1 = Wl + (size_t)nr1 * Kp + kb1;

    int fr = lane & 15;
    int fk = (lane >> 4) * 8;

    f32x4 acc[4][4] = {};

    for (int k0 = 0; k0 < Kp; k0 += 32) {
        GLL16(pAh0 + k0, &sAh[c0 * 8]);
        GLL16(pAh1 + k0, &sAh[c1 * 8]);
        GLL16(pAl0 + k0, &sAl[c0 * 8]);
        GLL16(pAl1 + k0, &sAl[c1 * 8]);
        GLL16(pWh0 + k0, &sWh[c0 * 8]);
        GLL16(pWh1 + k0, &sWh[c1 * 8]);
        GLL16(pWl0 + k0, &sWl[c0 * 8]);
        GLL16(pWl1 + k0, &sWl[c1 * 8]);
        __syncthreads();

        bf16x8 ah[4], al[4], wh[4], wl[4];
#pragma unroll
        for (int i = 0; i < 4; ++i) {
            ah[i] = *(const bf16x8*)&sAh[(wrow + i * 16 + fr) * 32 + fk];
            al[i] = *(const bf16x8*)&sAl[(wrow + i * 16 + fr) * 32 + fk];
            wh[i] = *(const bf16x8*)&sWh[(wcol + i * 16 + fr) * 32 + fk];
            wl[i] = *(const bf16x8*)&sWl[(wcol + i * 16 + fr) * 32 + fk];
        }
#pragma unroll
        for (int mi = 0; mi < 4; ++mi) {
#pragma unroll
            for (int ni = 0; ni < 4; ++ni) {
                acc[mi][ni] = __builtin_amdgcn_mfma_f32_16x16x32_bf16(ah[mi], wh[ni], acc[mi][ni], 0, 0, 0);
                acc[mi][ni] = __builtin_amdgcn_mfma_f32_16x16x32_bf16(ah[mi], wl[ni], acc[mi][ni], 0, 0, 0);
                acc[mi][ni] = __builtin_amdgcn_mfma_f32_16x16x32_bf16(al[mi], wh[ni], acc[mi][ni], 0, 0, 0);
            }
        }
        __syncthreads();
    }

    int crow = row0 + wrow + (lane >> 4) * 4;
    int ccol = col0 + wcol + (lane & 15);
#pragma unroll
    for (int ni = 0; ni < 4; ++ni) {
        int col = ccol + ni * 16;
        if (col >= N) continue;
        float bv = bias[col];
#pragma unroll
        for (int mi = 0; mi < 4; ++mi) {
#pragma unroll
            for (int j = 0; j < 4; ++j) {
                int row = crow + mi * 16 + j;
                if (row < M) C[(size_t)row * N + col] = acc[mi][ni][j] + bv;
            }
        }
    }
}

// ---------------- MFMA LSTM step: 1 wave/block, no LDS, direct L2->reg fragments ----------------
// block = 64 threads. grid.x = (np/16)*2. Each block: j-tile (16 cols) x 32 batch rows x 4 gates.
// pre[b][g*n+j] = xpre + sum_k h[b][k]*wh[g*n+j][k] + bh;  split-bf16 (3 products).
// Epilogue is lane-local (all 4 gates map to the same (row,col) in the same lane).
struct Frag12 {
    bf16x8 a0h, a1h, a0l, a1l;
    bf16x8 wfh, wih, woh, wgh;
    bf16x8 wfl, wil, wol, wgl;
};

#define MF(acc, va, vb) acc = __builtin_amdgcn_mfma_f32_16x16x32_bf16(va, vb, acc, 0, 0, 0)
#define COMPUTE(f)                                         \
    do {                                                   \
        MF(aF0, f.a0h, f.wfh); MF(aF0, f.a0h, f.wfl); MF(aF0, f.a0l, f.wfh); \
        MF(aI0, f.a0h, f.wih); MF(aI0, f.a0h, f.wil); MF(aI0, f.a0l, f.wih); \
        MF(aO0, f.a0h, f.woh); MF(aO0, f.a0h, f.wol); MF(aO0, f.a0l, f.woh); \
        MF(aG0, f.a0h, f.wgh); MF(aG0, f.a0h, f.wgl); MF(aG0, f.a0l, f.wgh); \
        MF(aF1, f.a1h, f.wfh); MF(aF1, f.a1h, f.wfl); MF(aF1, f.a1l, f.wfh); \
        MF(aI1, f.a1h, f.wih); MF(aI1, f.a1h, f.wil); MF(aI1, f.a1l, f.wih); \
        MF(aO1, f.a1h, f.woh); MF(aO1, f.a1h, f.wol); MF(aO1, f.a1l, f.woh); \
        MF(aG1, f.a1h, f.wgh); MF(aG1, f.a1h, f.wgl); MF(aG1, f.a1l, f.wgh); \
    } while (0)

__global__ __launch_bounds__(64) void lstm_step_mfma(
        const float* __restrict__ xpre,   // B x 4n (this timestep, bi already added)
        const u16* __restrict__ Hh,       // hprev hi, rows [0,64), stride Kp
        const u16* __restrict__ Hl,
        const u16* __restrict__ Whh,      // 4 x np x Kp (row/K zero-padded)
        const u16* __restrict__ Whl,
        const float* __restrict__ bh,     // 4n
        float* __restrict__ c,            // B x n (in place)
        u16* __restrict__ Oh,             // hout hi, rows [0,64), stride Kp
        u16* __restrict__ Ol,
        int n, int np, int Kp) {
    int lane = threadIdx.x;
    int jt = blockIdx.x >> 1, mb = blockIdx.x & 1;
    int j0 = jt * 16;
    int fr = lane & 15;
    int fk = (lane >> 4) * 8;

    const u16* pAh = Hh + (size_t)(mb * 32 + fr) * Kp + fk;
    const u16* pAl = Hl + (size_t)(mb * 32 + fr) * Kp + fk;
    const u16* pWh = Whh + (size_t)(j0 + fr) * Kp + fk;
    const u16* pWl = Whl + (size_t)(j0 + fr) * Kp + fk;
    size_t gstep = (size_t)np * Kp;
    size_t mstep = (size_t)16 * Kp;

    f32x4 aF0 = {}, aI0 = {}, aO0 = {}, aG0 = {};
    f32x4 aF1 = {}, aI1 = {}, aO1 = {}, aG1 = {};

    auto LOADF = [&](int k0) {
        Frag12 f;
        f.a0h = *(const bf16x8*)(pAh + k0);
        f.a1h = *(const bf16x8*)(pAh + mstep + k0);
        f.a0l = *(const bf16x8*)(pAl + k0);
        f.a1l = *(const bf16x8*)(pAl + mstep + k0);
        f.wfh = *(const bf16x8*)(pWh + k0);
        f.wih = *(const bf16x8*)(pWh + gstep + k0);
        f.woh = *(const bf16x8*)(pWh + 2 * gstep + k0);
        f.wgh = *(const bf16x8*)(pWh + 3 * gstep + k0);
        f.wfl = *(const bf16x8*)(pWl + k0);
        f.wil = *(const bf16x8*)(pWl + gstep + k0);
        f.wol = *(const bf16x8*)(pWl + 2 * gstep + k0);
        f.wgl = *(const bf16x8*)(pWl + 3 * gstep + k0);
        return f;
    };

    int niter = Kp >> 5;
    Frag12 fA = LOADF(0);
    Frag12 fB;
    int k = 32;
    for (int it = 0; it < niter; ++it) {
        if ((it & 1) == 0) {
            if (k < Kp) { fB = LOADF(k); k += 32; }
            COMPUTE(fA);
        } else {
            if (k < Kp) { fA = LOADF(k); k += 32; }
            COMPUTE(fB);
        }
    }

    int j = j0 + fr;
    if (j < n) {
        int G4 = 4 * n;
        float bf_ = bh[j], bi_ = bh[n + j], bo_ = bh[2 * n + j], bg_ = bh[3 * n + j];
#pragma unroll
        for (int mi = 0; mi < 2; ++mi) {
            f32x4 vF = mi ? aF1 : aF0;
            f32x4 vI = mi ? aI1 : aI0;
            f32x4 vO = mi ? aO1 : aO0;
            f32x4 vG = mi ? aG1 : aG0;
#pragma unroll
            for (int jr = 0; jr < 4; ++jr) {
                int b = mb * 32 + mi * 16 + (lane >> 4) * 4 + jr;
                const float* xp = xpre + (size_t)b * G4;
                float pf = vF[jr] + xp[j]         + bf_;
                float pi = vI[jr] + xp[n + j]     + bi_;
                float po = vO[jr] + xp[2 * n + j] + bo_;
                float pg = vG[jr] + xp[3 * n + j] + bg_;
                float f = 1.f / (1.f + expf(-pf));
                float i = 1.f / (1.f + expf(-pi));
                float o = 1.f / (1.f + expf(-po));
                float g = tanhf(pg);
                float cn = f * c[b * n + j] + i * g;
                c[b * n + j] = cn;
                float h = o * tanhf(cn);
                u16 hh = f2bf_rn(h);
                Oh[(size_t)b * Kp + j] = hh;
                Ol[(size_t)b * Kp + j] = f2bf_rn(h - bf2f(hh));
            }
        }
    }
}

extern "C" void kernel_launch(void* const* d_in, const int* in_sizes, int n_in,
                              void* d_out, int out_size, void* d_ws, size_t ws_size,
                              hipStream_t stream) {
    const int*   tok   = (const int*)d_in[0];
    const float* h0    = (const float*)d_in[1];
    const float* c0    = (const float*)d_in[2];
    const float* h1    = (const float*)d_in[3];
    const float* c1    = (const float*)d_in[4];
    const float* h2    = (const float*)d_in[5];
    const float* c2    = (const float*)d_in[6];
    const float* emb_w = (const float*)d_in[7];
    const float* wi[3] = {(const float*)d_in[8],  (const float*)d_in[12], (const float*)d_in[16]};
    const float* bi[3] = {(const float*)d_in[9],  (const float*)d_in[13], (const float*)d_in[17]};
    const float* wh[3] = {(const float*)d_in[10], (const float*)d_in[14], (const float*)d_in[18]};
    const float* bh[3] = {(const float*)d_in[11], (const float*)d_in[15], (const float*)d_in[19]};
    const float* dec_b = (const float*)d_in[20];
    const float* hinit[3] = {h0, h1, h2};
    const float* cinit[3] = {c0, c1, c2};
    const int din[3]  = {NINP, NHID, NHID};
    const int dout[3] = {NHID, NHID, NINP};

    // ---- workspace layout (bytes), total 160,853,504 ----
    char* base = (char*)d_ws;
    float* P   = (float*)(base + 0);            // 4480*4600*4      = 82,432,000
    float* cb  = (float*)(base + 82432000);     // 64*1150*4        =    294,400
    u16* A0h   = (u16*)(base + 82726400);       // 4480*416*2       =  3,727,360
    u16* A0l   = (u16*)(base + 86453760);       //                  =  3,727,360
    u16* HA[3] = {(u16*)(base + 90181120),      // 4544*1152*2      = 10,469,376
                  (u16*)(base + 111119872),     // 4544*1152*2
                  (u16*)(base + 132058624)};    // 4544*416*2       =  3,780,608
    u16* HL[3] = {(u16*)(base + 100650496),
                  (u16*)(base + 121589248),
                  (u16*)(base + 135839232)};
    u16* Wsh   = (u16*)(base + 139619840);      // max split buf    = 10,616,832
    u16* Wsl   = (u16*)(base + 150236672);      //                  = 10,616,832
    u16* DWh   = (u16*)(base + 0);              // decoder W split reuses P: 27,687,296
    u16* DWl   = (u16*)(base + 27687296);

    // 1) fused embedding gather + bf16 split (layer-0 A operand, Kp=416)
    embed_split<<<(MROWS * 416 + 255) / 256, 256, 0, stream>>>(tok, emb_w, A0h, A0l);

    const u16* Ain_h = A0h;
    const u16* Ain_l = A0l;
    for (int l = 0; l < 3; ++l) {
        int G      = 4 * dout[l];
        int Kin    = din[l];
        int KpIn   = (Kin + 31) & ~31;
        int n      = dout[l];
        int np     = (n + 15) & ~15;
        int KpRec  = (n + 31) & ~31;

        // 2) split wi -> Ws; x_pre = A @ wi^T + bi  (M x G)
        split_kernel<<<((size_t)G * KpIn + 255) / 256, 256, 0, stream>>>(wi[l], Wsh, Wsl, G, Kin, KpIn);
        dim3 g1(MROWS / 128, (G + 127) / 128);
        gemm_mfma<<<g1, 256, 0, stream>>>(Ain_h, Ain_l, Wsh, Wsl, bi[l], P, MROWS, G, KpIn);

        // 3) split wh -> Ws (reuses buffer; gemm above is stream-ordered before this)
        split_wh_kernel<<<(4 * np * KpRec + 255) / 256, 256, 0, stream>>>(wh[l], Wsh, Wsl, n, np, KpRec);

        // 4) initial h (rows [0,64) of HA) and c state
        split_kernel<<<((size_t)64 * KpRec + 255) / 256, 256, 0, stream>>>(hinit[l], HA[l], HL[l], 64, n, KpRec);
        int bn = BATCH * n;
        copy_kernel<<<(bn + 255) / 256, 256, 0, stream>>>(cinit[l], cb, bn);

        // 5) scan: step t reads h rows [t*64,..), writes rows [(t+1)*64,..)
        int grid = (np / 16) * 2;
        for (int t = 0; t < T_STEPS; ++t) {
            lstm_step_mfma<<<grid, 64, 0, stream>>>(
                P + (size_t)t * BATCH * G,
                HA[l] + (size_t)t * 64 * KpRec, HL[l] + (size_t)t * 64 * KpRec,
                Wsh, Wsl, bh[l], cb,
                HA[l] + (size_t)(t + 1) * 64 * KpRec, HL[l] + (size_t)(t + 1) * 64 * KpRec,
                n, np, KpRec);
        }

        // this layer's h history (rows 64..) is the next layer's A operand
        Ain_h = HA[l] + (size_t)64 * KpRec;
        Ain_l = HL[l] + (size_t)64 * KpRec;
    }

    // 6) decoder: out = h3 @ emb_w^T + dec_b  (4480 x 33278), Kp=416
    {
        int Kp = 416;
        split_kernel<<<((size_t)NTOKEN * Kp + 255) / 256, 256, 0, stream>>>(emb_w, DWh, DWl, NTOKEN, NINP, Kp);
        dim3 g2(MROWS / 128, (NTOKEN + 127) / 128);
        gemm_mfma<<<g2, 256, 0, stream>>>(Ain_h, Ain_l, DWh, DWl, dec_b, (float*)d_out, MROWS, NTOKEN, Kp);
    }
}